// Round 2
// baseline (781.656 us; speedup 1.0000x reference)
//
#include <hip/hip_runtime.h>
#include <hip/hip_bf16.h>

// Attention_44006234915573 — windowed attention, MI355X/gfx950
// B=256, D=128, HEADS=4, DH=32, N=625 (padded to 640), bf16 MFMA pipeline.
//
// R2: k_attn keeps only per-wave P in LDS (16KB, XOR-swizzled), K/V/Q/bias read
// direct from global (L2-resident per block) -> no barriers, occupancy-bound by
// VGPR not LDS. k_qkv/k_out use pre-converted bf16 weights (k_prep) and a
// 10x finer grid (one block per 64-row tile).
//
// ws layout (bytes):
//   [0,   41943040)   Q   bf16 [1024][640][32]   (pre-scaled by SCALE*LOG2E)
//   [+1x, +2x)        K   bf16 [1024][640][32]
//   [+2x, +3x)        Vt  bf16 [1024][32][640]
//   [+3x, +4x)        O   bf16 [256][640][128]   (head-major channels)
//   [167772160, +3.3M) bias_t bf16 [4][640][640]
//   [171048960, +96K)  W_qkv bf16 [384][128]
//   [171147264, +32K)  W_out bf16 [128][128]
// total 171,180,032 bytes of d_ws.

typedef __attribute__((ext_vector_type(8))) short short8;
typedef __attribute__((ext_vector_type(4))) float f32x4;

#define MFMA16(a, b, c) __builtin_amdgcn_mfma_f32_16x16x32_bf16((a), (b), (c), 0, 0, 0)

__device__ __forceinline__ unsigned short f2b(float f) {
  __hip_bfloat16 h = __float2bfloat16(f);
  return *reinterpret_cast<unsigned short*>(&h);
}
__device__ __forceinline__ float b2f(unsigned short s) {
  union { unsigned u; float f; } x; x.u = ((unsigned)s) << 16;
  return x.f;
}

constexpr float LOG2E_F = 1.4426950408889634f;
constexpr float QSCALE  = 0.17677669529663687f * 1.4426950408889634f;  // dh^-0.5 * log2(e)

// swizzled P index: pitch 128 elems, XOR col bit4 with row[3:2] -> write banks
// spread (2 lanes/bank = free), reads ~2-way.
#define PIDX(r, c) ((r) * 128 + ((c) ^ (((r) & 12) << 2)))

// ---------------------------------------------------------------- weight cvt
__global__ __launch_bounds__(256) void k_prep(const float* __restrict__ wqkv,
                                              const float* __restrict__ wout,
                                              unsigned short* __restrict__ wq_bf,
                                              unsigned short* __restrict__ wo_bf) {
  int id = blockIdx.x * 256 + threadIdx.x;   // 65536 = 49152 + 16384
  if (id < 49152) wq_bf[id] = f2b(wqkv[id]);
  else            wo_bf[id - 49152] = f2b(wout[id - 49152]);
}

// ---------------------------------------------------------------- bias expand
__global__ __launch_bounds__(256) void k_bias(const float* __restrict__ table,
                                              const int* __restrict__ idx,
                                              unsigned short* __restrict__ bt) {
  int id = blockIdx.x * 256 + threadIdx.x;  // 0 .. 409599 over (j,i)
  int i = id % 640;
  int j = id / 640;
  float v0, v1, v2, v3;
  if (j >= 625) {
    v0 = v1 = v2 = v3 = -1e30f;             // masks padded K columns via exp2 -> 0
  } else if (i >= 625) {
    v0 = v1 = v2 = v3 = 0.f;                // padded Q rows: harmless finite
  } else {
    int ix = idx[i * 625 + j];
    const float* tr = table + ix * 4;
    v0 = tr[0] * LOG2E_F; v1 = tr[1] * LOG2E_F;
    v2 = tr[2] * LOG2E_F; v3 = tr[3] * LOG2E_F;
  }
  int o = j * 640 + i;
  bt[o]           = f2b(v0);
  bt[409600 + o]  = f2b(v1);
  bt[819200 + o]  = f2b(v2);
  bt[1228800 + o] = f2b(v3);
}

// ---------------------------------------------------------------- QKV proj
// one block per (batch, 64-row tile); W bf16 read direct from global (L2-hot)
__global__ __launch_bounds__(256) void k_qkv(const float* __restrict__ x,
                                             const unsigned short* __restrict__ wbf,
                                             unsigned short* __restrict__ qws,
                                             unsigned short* __restrict__ kws,
                                             unsigned short* __restrict__ vtws) {
  int blk = blockIdx.x;
  int b = blk / 10, tile = blk % 10;
  int t = threadIdx.x, w = t >> 6, lane = t & 63, r16 = lane & 15, g = lane >> 4;
  int nr = tile * 64 + w * 16;              // wave's 16 rows
  int n = nr + r16;
  bool nv = n < 625;
  const float* xb = x + (size_t)b * 80000 + n;
  short8 a[4];
#pragma unroll
  for (int kk = 0; kk < 4; ++kk) {
    short8 av;
#pragma unroll
    for (int jj = 0; jj < 8; ++jj) {
      int d = kk * 32 + g * 8 + jj;
      av[jj] = (short)f2b(nv ? xb[d * 625] : 0.f);
    }
    a[kk] = av;
  }
  f32x4 acc[24];
#pragma unroll
  for (int nf = 0; nf < 24; ++nf) acc[nf] = (f32x4){0.f, 0.f, 0.f, 0.f};
#pragma unroll
  for (int kk = 0; kk < 4; ++kk) {
#pragma unroll
    for (int nf = 0; nf < 24; ++nf) {
      short8 bf = *reinterpret_cast<const short8*>(wbf + (nf * 16 + r16) * 128 + kk * 32 + g * 8);
      acc[nf] = MFMA16(a[kk], bf, acc[nf]);
    }
  }
#pragma unroll
  for (int nf = 0; nf < 24; ++nf) {
    int c0 = nf * 16;
    int sel = c0 >> 7, hh = (c0 & 127) >> 5, t0 = (c0 & 31);
    float mul = (sel == 0) ? QSCALE : 1.f;
    size_t base = (size_t)(b * 4 + hh);
    if (sel < 2) {
      unsigned short* dst = (sel ? kws : qws) + (base * 640 + nr + 4 * g) * 32 + t0 + r16;
#pragma unroll
      for (int rr = 0; rr < 4; ++rr) dst[rr * 32] = f2b(acc[nf][rr] * mul);
    } else {
      ushort4 pv;
      pv.x = f2b(acc[nf][0]); pv.y = f2b(acc[nf][1]);
      pv.z = f2b(acc[nf][2]); pv.w = f2b(acc[nf][3]);
      *reinterpret_cast<ushort4*>(vtws + (base * 32 + t0 + r16) * 640 + nr + 4 * g) = pv;
    }
  }
}

// ---------------------------------------------------------------- attention
// one block per (b,h); K/V/Q/bias from global (L2-resident); no-max softmax in
// exp2 domain; P via per-wave-private swizzled LDS; zero barriers.
__global__ __launch_bounds__(256) void k_attn(const unsigned short* __restrict__ qws,
                                              const unsigned short* __restrict__ kws,
                                              const unsigned short* __restrict__ vtws,
                                              const unsigned short* __restrict__ bt,
                                              unsigned short* __restrict__ ows) {
  __shared__ __align__(16) unsigned short Pl[64 * 128];
  int bh = blockIdx.x, b = bh >> 2, h = bh & 3;
  int t = threadIdx.x, w = t >> 6, lane = t & 63, r16 = lane & 15, g = lane >> 4;
  const unsigned short* Kg = kws + (size_t)bh * 20480;
  const unsigned short* Vg = vtws + (size_t)bh * 20480;
  const unsigned short* Qg = qws + (size_t)bh * 20480;
  const unsigned short* bth = bt + (size_t)h * 409600;
  for (int qt = 0; qt < 10; ++qt) {
    int i0 = qt * 64 + w * 16;              // wave's 16 Q rows
    short8 qa = *reinterpret_cast<const short8*>(Qg + (i0 + r16) * 32 + g * 8);
    f32x4 oacc[2];
    oacc[0] = (f32x4){0.f, 0.f, 0.f, 0.f};
    oacc[1] = (f32x4){0.f, 0.f, 0.f, 0.f};
    float sp0 = 0.f, sp1 = 0.f, sp2 = 0.f, sp3 = 0.f;
    for (int c = 0; c < 5; ++c) {
      int j0 = c * 128;
      f32x4 s[8];
      f32x4 zz = (f32x4){0.f, 0.f, 0.f, 0.f};
#pragma unroll
      for (int jf = 0; jf < 8; ++jf) {
        short8 kb = *reinterpret_cast<const short8*>(Kg + (j0 + jf * 16 + r16) * 32 + g * 8);
        s[jf] = MFMA16(qa, kb, zz);
      }
#pragma unroll
      for (int jf = 0; jf < 8; ++jf) {
        int j = j0 + jf * 16 + r16;
        ushort4 bv = *reinterpret_cast<const ushort4*>(bth + (size_t)j * 640 + i0 + 4 * g);
        float p0 = __builtin_amdgcn_exp2f(s[jf][0] + b2f(bv.x));
        float p1 = __builtin_amdgcn_exp2f(s[jf][1] + b2f(bv.y));
        float p2 = __builtin_amdgcn_exp2f(s[jf][2] + b2f(bv.z));
        float p3 = __builtin_amdgcn_exp2f(s[jf][3] + b2f(bv.w));
        sp0 += p0; sp1 += p1; sp2 += p2; sp3 += p3;
        int pr = w * 16 + 4 * g;
        int pc = jf * 16 + r16;
        Pl[PIDX(pr + 0, pc)] = f2b(p0);
        Pl[PIDX(pr + 1, pc)] = f2b(p1);
        Pl[PIDX(pr + 2, pc)] = f2b(p2);
        Pl[PIDX(pr + 3, pc)] = f2b(p3);
      }
      asm volatile("s_waitcnt lgkmcnt(0)" ::: "memory");  // P writes -> P reads (intra-wave)
#pragma unroll
      for (int ks = 0; ks < 4; ++ks) {
        short8 pa = *reinterpret_cast<short8*>(&Pl[PIDX(w * 16 + r16, ks * 32 + g * 8)]);
#pragma unroll
        for (int f = 0; f < 2; ++f) {
          short8 vb = *reinterpret_cast<const short8*>(Vg + (f * 16 + r16) * 640 + j0 + ks * 32 + g * 8);
          oacc[f] = MFMA16(pa, vb, oacc[f]);
        }
      }
    }
#pragma unroll
    for (int m = 1; m < 16; m <<= 1) {
      sp0 += __shfl_xor(sp0, m, 64);
      sp1 += __shfl_xor(sp1, m, 64);
      sp2 += __shfl_xor(sp2, m, 64);
      sp3 += __shfl_xor(sp3, m, 64);
    }
    float rc0 = 1.f / sp0, rc1 = 1.f / sp1, rc2 = 1.f / sp2, rc3 = 1.f / sp3;
    size_t ob = ((size_t)b * 640 + i0 + 4 * g) * 128 + h * 32;
#pragma unroll
    for (int f = 0; f < 2; ++f) {
      ows[ob + 0 * 128 + f * 16 + r16] = f2b(oacc[f][0] * rc0);
      ows[ob + 1 * 128 + f * 16 + r16] = f2b(oacc[f][1] * rc1);
      ows[ob + 2 * 128 + f * 16 + r16] = f2b(oacc[f][2] * rc2);
      ows[ob + 3 * 128 + f * 16 + r16] = f2b(oacc[f][3] * rc3);
    }
  }
}

// ---------------------------------------------------------------- out proj
// one block per (batch, 64-row tile); W_out bf16 direct from global
__global__ __launch_bounds__(256) void k_out(const unsigned short* __restrict__ ows,
                                             const unsigned short* __restrict__ wbf,
                                             float* __restrict__ out) {
  int blk = blockIdx.x;
  int b = blk / 10, tile = blk % 10;
  int t = threadIdx.x, w = t >> 6, lane = t & 63, r16 = lane & 15, g = lane >> 4;
  const unsigned short* Ob = ows + (size_t)b * 640 * 128;
  float* outb = out + (size_t)b * 128 * 625;
  int n0 = tile * 64;
  f32x4 acc[2][4];
#pragma unroll
  for (int mi = 0; mi < 2; ++mi)
#pragma unroll
    for (int f = 0; f < 4; ++f) acc[mi][f] = (f32x4){0.f, 0.f, 0.f, 0.f};
#pragma unroll
  for (int kk = 0; kk < 4; ++kk) {
    short8 bfr[4];
#pragma unroll
    for (int f = 0; f < 4; ++f)
      bfr[f] = *reinterpret_cast<const short8*>(Ob + (n0 + f * 16 + r16) * 128 + kk * 32 + g * 8);
#pragma unroll
    for (int mi = 0; mi < 2; ++mi) {
      short8 afr = *reinterpret_cast<const short8*>(wbf + (w * 32 + mi * 16 + r16) * 128 + kk * 32 + g * 8);
#pragma unroll
      for (int f = 0; f < 4; ++f) acc[mi][f] = MFMA16(afr, bfr[f], acc[mi][f]);
    }
  }
#pragma unroll
  for (int mi = 0; mi < 2; ++mi)
#pragma unroll
    for (int f = 0; f < 4; ++f) {
      int n = n0 + f * 16 + r16;
      if (n < 625) {
        int dout = w * 32 + mi * 16 + 4 * g;
        outb[(dout + 0) * 625 + n] = acc[mi][f][0];
        outb[(dout + 1) * 625 + n] = acc[mi][f][1];
        outb[(dout + 2) * 625 + n] = acc[mi][f][2];
        outb[(dout + 3) * 625 + n] = acc[mi][f][3];
      }
    }
}

// ---------------------------------------------------------------- launch
extern "C" void kernel_launch(void* const* d_in, const int* in_sizes, int n_in,
                              void* d_out, int out_size, void* d_ws, size_t ws_size,
                              hipStream_t stream) {
  const float* x     = (const float*)d_in[0];
  const float* wqkv  = (const float*)d_in[1];
  const float* wout  = (const float*)d_in[2];
  const float* table = (const float*)d_in[3];
  const int*   idx   = (const int*)d_in[4];
  float* out = (float*)d_out;

  char* ws = (char*)d_ws;  // requires ~171.2 MB
  unsigned short* qws   = (unsigned short*)(ws);
  unsigned short* kws   = (unsigned short*)(ws + 41943040);
  unsigned short* vtws  = (unsigned short*)(ws + 83886080);
  unsigned short* ows   = (unsigned short*)(ws + 125829120);
  unsigned short* bt    = (unsigned short*)(ws + 167772160);
  unsigned short* wq_bf = (unsigned short*)(ws + 171048960);
  unsigned short* wo_bf = (unsigned short*)(ws + 171147264);

  k_prep<<<dim3(256), dim3(256), 0, stream>>>(wqkv, wout, wq_bf, wo_bf);
  k_bias<<<dim3(1600), dim3(256), 0, stream>>>(table, idx, bt);
  k_qkv<<<dim3(2560), dim3(256), 0, stream>>>(x, wq_bf, qws, kws, vtws);
  k_attn<<<dim3(1024), dim3(256), 0, stream>>>(qws, kws, vtws, bt, ows);
  k_out<<<dim3(2560), dim3(256), 0, stream>>>(ows, wo_bf, out);
}

// Round 3
// 383.962 us; speedup vs baseline: 2.0358x; 2.0358x over previous
//
#include <hip/hip_runtime.h>
#include <hip/hip_bf16.h>

// Attention_44006234915573 — windowed attention, MI355X/gfx950
// B=256, D=128, HEADS=4, DH=32, N=625 (padded to 640), bf16 MFMA pipeline.
//
// R3: k_attn = 512-thread blocks (8 waves = 2/SIMD), K/V staged in LDS
// (conflict-free layouts), per-wave swizzled P (no inter-wave barriers after
// stage), bias folded into the QK MFMA C-operand, row-sums via MFMA with
// B=ones (no shuffle reduce). k_qkv stages the x-tile in LDS for coalesced
// global loads. k_out as R1.
//
// ws layout (bytes):
//   [0,   41943040)    Q   bf16 [1024][640][32]   (pre-scaled by SCALE*LOG2E)
//   [+1x, +2x)         K   bf16 [1024][640][32]
//   [+2x, +3x)         Vt  bf16 [1024][32][640]
//   [+3x, +4x)         O   bf16 [256][640][128]   (head-major channels)
//   [167772160, +3.3M) bias_t bf16 [4][640][640]
// total 171,048,960 bytes of d_ws.

typedef __attribute__((ext_vector_type(8))) short short8;
typedef __attribute__((ext_vector_type(4))) float f32x4;

#define MFMA16(a, b, c) __builtin_amdgcn_mfma_f32_16x16x32_bf16((a), (b), (c), 0, 0, 0)

__device__ __forceinline__ unsigned short f2b(float f) {
  __hip_bfloat16 h = __float2bfloat16(f);
  return *reinterpret_cast<unsigned short*>(&h);
}
__device__ __forceinline__ float b2f(unsigned short s) {
  union { unsigned u; float f; } x; x.u = ((unsigned)s) << 16;
  return x.f;
}

constexpr float LOG2E_F = 1.4426950408889634f;
constexpr float QSCALE  = 0.17677669529663687f * 1.4426950408889634f;  // dh^-0.5 * log2(e)

// swizzled P index (per-wave 16x128 tile): XOR col bit4..5 with row bits 2..3.
// writes: 32 distinct banks (2 half-word lanes/bank); reads: 8-cycle optimal.
#define PIDX(r, c) ((r) * 128 + ((c) ^ (((r) & 12) << 2)))

// ---------------------------------------------------------------- bias expand
__global__ __launch_bounds__(256) void k_bias(const float* __restrict__ table,
                                              const int* __restrict__ idx,
                                              unsigned short* __restrict__ bt) {
  int id = blockIdx.x * 256 + threadIdx.x;  // 0 .. 409599 over (j,i)
  int i = id % 640;
  int j = id / 640;
  float v0, v1, v2, v3;
  if (j >= 625) {
    v0 = v1 = v2 = v3 = -1e30f;             // masks padded K columns via exp2 -> 0
  } else if (i >= 625) {
    v0 = v1 = v2 = v3 = 0.f;                // padded Q rows: harmless finite
  } else {
    int ix = idx[i * 625 + j];
    const float* tr = table + ix * 4;
    v0 = tr[0] * LOG2E_F; v1 = tr[1] * LOG2E_F;
    v2 = tr[2] * LOG2E_F; v3 = tr[3] * LOG2E_F;
  }
  int o = j * 640 + i;
  bt[o]           = f2b(v0);
  bt[409600 + o]  = f2b(v1);
  bt[819200 + o]  = f2b(v2);
  bt[1228800 + o] = f2b(v3);
}

// ---------------------------------------------------------------- QKV proj
// one block per batch; W_qkv bf16 in LDS; x-tile staged f32 in LDS so global
// loads are coalesced (row-major) and the transpose happens on LDS reads.
__global__ __launch_bounds__(256) void k_qkv(const float* __restrict__ x,
                                             const float* __restrict__ wqkv,
                                             unsigned short* __restrict__ qws,
                                             unsigned short* __restrict__ kws,
                                             unsigned short* __restrict__ vtws) {
  __shared__ unsigned short Wl[384 * 136];   // 102 KB
  __shared__ float Xf[128 * 65];             // 33.3 KB  [d][n] pad 65
  int b = blockIdx.x, t = threadIdx.x;
  for (int it = 0; it < 48; ++it) {
    int g4 = it * 256 + t;                  // 12288 float4 of W
    int c = g4 >> 5, d0 = (g4 & 31) << 2;
    float4 w4 = *reinterpret_cast<const float4*>(wqkv + c * 128 + d0);
    ushort4 p;
    p.x = f2b(w4.x); p.y = f2b(w4.y); p.z = f2b(w4.z); p.w = f2b(w4.w);
    *reinterpret_cast<ushort4*>(&Wl[c * 136 + d0]) = p;
  }
  int w = t >> 6, lane = t & 63, r16 = lane & 15, g = lane >> 4;
  const float* xb = x + (size_t)b * 80000;
  for (int tile = 0; tile < 10; ++tile) {
    int n0 = tile * 64;
    __syncthreads();                         // Xf safe to overwrite (and W ready)
    for (int it = 0; it < 32; ++it) {
      int idx = it * 256 + t;                // 8192 = 128 d x 64 n
      int d = idx >> 6, nc = idx & 63;
      int n = n0 + nc;
      Xf[d * 65 + nc] = (n < 625) ? xb[d * 625 + n] : 0.f;
    }
    __syncthreads();
    int nr = n0 + w * 16;                    // wave's 16 rows
    short8 a[4];
#pragma unroll
    for (int kk = 0; kk < 4; ++kk) {
      short8 av;
#pragma unroll
      for (int jj = 0; jj < 8; ++jj)
        av[jj] = (short)f2b(Xf[(kk * 32 + g * 8 + jj) * 65 + w * 16 + r16]);
      a[kk] = av;
    }
    f32x4 acc[24];
#pragma unroll
    for (int nf = 0; nf < 24; ++nf) acc[nf] = (f32x4){0.f, 0.f, 0.f, 0.f};
#pragma unroll
    for (int kk = 0; kk < 4; ++kk) {
#pragma unroll
      for (int nf = 0; nf < 24; ++nf) {
        short8 bf = *reinterpret_cast<short8*>(&Wl[(nf * 16 + r16) * 136 + kk * 32 + g * 8]);
        acc[nf] = MFMA16(a[kk], bf, acc[nf]);
      }
    }
#pragma unroll
    for (int nf = 0; nf < 24; ++nf) {
      int c0 = nf * 16;
      int sel = c0 >> 7, hh = (c0 & 127) >> 5, t0 = (c0 & 31);
      float mul = (sel == 0) ? QSCALE : 1.f;
      size_t base = (size_t)(b * 4 + hh);
      if (sel < 2) {
        unsigned short* dst = (sel ? kws : qws) + (base * 640 + nr + 4 * g) * 32 + t0 + r16;
#pragma unroll
        for (int rr = 0; rr < 4; ++rr) dst[rr * 32] = f2b(acc[nf][rr] * mul);
      } else {
        ushort4 pv;
        pv.x = f2b(acc[nf][0]); pv.y = f2b(acc[nf][1]);
        pv.z = f2b(acc[nf][2]); pv.w = f2b(acc[nf][3]);
        *reinterpret_cast<ushort4*>(vtws + (base * 32 + t0 + r16) * 640 + nr + 4 * g) = pv;
      }
    }
  }
}

// ---------------------------------------------------------------- attention
// one block (512 thr, 8 waves) per (b,h); K/V in LDS; bias as MFMA C-in;
// row-sums via MFMA with B=ones; per-wave private P; one barrier total.
__global__ __launch_bounds__(512) void k_attn(const unsigned short* __restrict__ qws,
                                              const unsigned short* __restrict__ kws,
                                              const unsigned short* __restrict__ vtws,
                                              const unsigned short* __restrict__ bt,
                                              unsigned short* __restrict__ ows) {
  __shared__ __align__(16) unsigned short Kl[640 * 32];   // 40960 B, stride 64B
  __shared__ __align__(16) unsigned short Vl[32 * 648];   // 41472 B, pad->8cyc reads
  __shared__ __align__(16) unsigned short Pl[128 * 128];  // 32 KB, 16 rows/wave
  int bh = blockIdx.x, b = bh >> 2, h = bh & 3;
  int t = threadIdx.x, w = t >> 6, lane = t & 63, r16 = lane & 15, g = lane >> 4;
  const unsigned short* Kg = kws + (size_t)bh * 20480;
  const unsigned short* Vg = vtws + (size_t)bh * 20480;
  for (int it = 0; it < 5; ++it) {
    int e8 = (it * 512 + t) * 8;             // 20480 elems of K
    *reinterpret_cast<short8*>(&Kl[e8]) = *reinterpret_cast<const short8*>(Kg + e8);
  }
  for (int it = 0; it < 5; ++it) {
    int v8 = it * 512 + t;                   // 2560 8-elem blocks of V
    int d = v8 / 80, nb = (v8 % 80) * 8;
    *reinterpret_cast<short8*>(&Vl[d * 648 + nb]) =
        *reinterpret_cast<const short8*>(Vg + d * 640 + nb);
  }
  __syncthreads();
  const unsigned short* Qg = qws + (size_t)bh * 20480;
  const unsigned short* bth = bt + (size_t)h * 409600;
  short8 ones;
#pragma unroll
  for (int jj = 0; jj < 8; ++jj) ones[jj] = (short)0x3F80;  // bf16 1.0
  for (int p = 0; p < 5; ++p) {
    int i0 = p * 128 + w * 16;               // wave's 16 Q rows
    short8 qa = *reinterpret_cast<const short8*>(Qg + (i0 + r16) * 32 + g * 8);
    f32x4 oacc[2];
    oacc[0] = (f32x4){0.f, 0.f, 0.f, 0.f};
    oacc[1] = (f32x4){0.f, 0.f, 0.f, 0.f};
    f32x4 sacc = (f32x4){0.f, 0.f, 0.f, 0.f};
    for (int c = 0; c < 5; ++c) {
      int j0 = c * 128;
      f32x4 s[8];
#pragma unroll
      for (int jf = 0; jf < 8; ++jf) {
        int j = j0 + jf * 16 + r16;
        ushort4 bv = *reinterpret_cast<const ushort4*>(bth + (size_t)j * 640 + i0 + 4 * g);
        f32x4 bc;
        bc[0] = b2f(bv.x); bc[1] = b2f(bv.y); bc[2] = b2f(bv.z); bc[3] = b2f(bv.w);
        short8 kb = *reinterpret_cast<short8*>(&Kl[(j0 + jf * 16 + r16) * 32 + g * 8]);
        s[jf] = MFMA16(qa, kb, bc);          // S = QK^T + bias (log2 domain)
      }
#pragma unroll
      for (int jf = 0; jf < 8; ++jf) {
        int pr = w * 16 + 4 * g;
        int pc = jf * 16 + r16;
        Pl[PIDX(pr + 0, pc)] = f2b(__builtin_amdgcn_exp2f(s[jf][0]));
        Pl[PIDX(pr + 1, pc)] = f2b(__builtin_amdgcn_exp2f(s[jf][1]));
        Pl[PIDX(pr + 2, pc)] = f2b(__builtin_amdgcn_exp2f(s[jf][2]));
        Pl[PIDX(pr + 3, pc)] = f2b(__builtin_amdgcn_exp2f(s[jf][3]));
      }
      asm volatile("s_waitcnt lgkmcnt(0)" ::: "memory");  // P writes -> P reads (intra-wave)
#pragma unroll
      for (int ks = 0; ks < 4; ++ks) {
        short8 pa = *reinterpret_cast<short8*>(&Pl[PIDX(w * 16 + r16, ks * 32 + g * 8)]);
        sacc = MFMA16(pa, ones, sacc);       // row-sums, every lane gets its row
#pragma unroll
        for (int f = 0; f < 2; ++f) {
          short8 vb = *reinterpret_cast<short8*>(&Vl[(f * 16 + r16) * 648 + j0 + ks * 32 + g * 8]);
          oacc[f] = MFMA16(pa, vb, oacc[f]);
        }
      }
    }
    size_t ob = ((size_t)b * 640 + i0 + 4 * g) * 128 + h * 32;
#pragma unroll
    for (int rr = 0; rr < 4; ++rr) {
      float rc = 1.f / sacc[rr];
      ows[ob + rr * 128 + 0 * 16 + r16]  = f2b(oacc[0][rr] * rc);
      ows[ob + rr * 128 + 1 * 16 + r16]  = f2b(oacc[1][rr] * rc);
    }
  }
}

// ---------------------------------------------------------------- out proj
__global__ __launch_bounds__(256) void k_out(const unsigned short* __restrict__ ows,
                                             const float* __restrict__ wout,
                                             float* __restrict__ out) {
  __shared__ unsigned short Wl[128 * 136];
  int b = blockIdx.x, t = threadIdx.x;
  for (int it = 0; it < 16; ++it) {
    int g4 = it * 256 + t;                  // 4096 float4 of W_out
    int row = g4 >> 5, d0 = (g4 & 31) << 2;
    float4 w4 = *reinterpret_cast<const float4*>(wout + row * 128 + d0);
    ushort4 p;
    p.x = f2b(w4.x); p.y = f2b(w4.y); p.z = f2b(w4.z); p.w = f2b(w4.w);
    *reinterpret_cast<ushort4*>(&Wl[row * 136 + d0]) = p;
  }
  __syncthreads();
  int w = t >> 6, lane = t & 63, r16 = lane & 15, g = lane >> 4;
  const unsigned short* Ob = ows + (size_t)b * 640 * 128;
  float* outb = out + (size_t)b * 128 * 625;
  for (int tile = 0; tile < 10; ++tile) {
    int n0 = tile * 64;
    f32x4 acc[2][4];
#pragma unroll
    for (int mi = 0; mi < 2; ++mi)
#pragma unroll
      for (int f = 0; f < 4; ++f) acc[mi][f] = (f32x4){0.f, 0.f, 0.f, 0.f};
#pragma unroll
    for (int kk = 0; kk < 4; ++kk) {
      short8 bfr[4];
#pragma unroll
      for (int f = 0; f < 4; ++f)
        bfr[f] = *reinterpret_cast<const short8*>(Ob + (n0 + f * 16 + r16) * 128 + kk * 32 + g * 8);
#pragma unroll
      for (int mi = 0; mi < 2; ++mi) {
        short8 afr = *reinterpret_cast<short8*>(&Wl[(w * 32 + mi * 16 + r16) * 136 + kk * 32 + g * 8]);
#pragma unroll
        for (int f = 0; f < 4; ++f) acc[mi][f] = MFMA16(afr, bfr[f], acc[mi][f]);
      }
    }
#pragma unroll
    for (int mi = 0; mi < 2; ++mi)
#pragma unroll
      for (int f = 0; f < 4; ++f) {
        int n = n0 + f * 16 + r16;
        if (n < 625) {
          int dout = w * 32 + mi * 16 + 4 * g;
          outb[(dout + 0) * 625 + n] = acc[mi][f][0];
          outb[(dout + 1) * 625 + n] = acc[mi][f][1];
          outb[(dout + 2) * 625 + n] = acc[mi][f][2];
          outb[(dout + 3) * 625 + n] = acc[mi][f][3];
        }
      }
  }
}

// ---------------------------------------------------------------- launch
extern "C" void kernel_launch(void* const* d_in, const int* in_sizes, int n_in,
                              void* d_out, int out_size, void* d_ws, size_t ws_size,
                              hipStream_t stream) {
  const float* x     = (const float*)d_in[0];
  const float* wqkv  = (const float*)d_in[1];
  const float* wout  = (const float*)d_in[2];
  const float* table = (const float*)d_in[3];
  const int*   idx   = (const int*)d_in[4];
  float* out = (float*)d_out;

  char* ws = (char*)d_ws;  // requires ~171 MB
  unsigned short* qws  = (unsigned short*)(ws);
  unsigned short* kws  = (unsigned short*)(ws + 41943040);
  unsigned short* vtws = (unsigned short*)(ws + 83886080);
  unsigned short* ows  = (unsigned short*)(ws + 125829120);
  unsigned short* bt   = (unsigned short*)(ws + 167772160);

  k_bias<<<dim3(1600), dim3(256), 0, stream>>>(table, idx, bt);
  k_qkv<<<dim3(256), dim3(256), 0, stream>>>(x, wqkv, qws, kws, vtws);
  k_attn<<<dim3(1024), dim3(512), 0, stream>>>(qws, kws, vtws, bt, ows);
  k_out<<<dim3(256), dim3(256), 0, stream>>>(ows, wout, out);
}

// Round 4
// 362.791 us; speedup vs baseline: 2.1546x; 1.0584x over previous
//
#include <hip/hip_runtime.h>
#include <hip/hip_bf16.h>

// Attention_44006234915573 — windowed attention, MI355X/gfx950
// B=256, D=128, HEADS=4, DH=32, N=625 (padded to 640).
//
// R4: k_attn rewritten on swapped 32x32x16 MFMA (T12 structure):
//  - S^T = mfma(K,Q) -> each lane owns P-row values in regs (no P LDS)
//  - softmax in-register: exp2 + v_cvt_pk_bf16_f32 + v_permlane32_swap_b32
//  - row sums via mfma with A=ones (all 16 acc regs = row sum)
//  - bias as MFMA C-operand from coalesced [h][j/4][i][4] bf16 layout
//  - K in LDS pitch 40 (conflict-free b128 phases), V pitch 648
// k_qkv: grid 2560, x-tile in LDS (33KB), bf16 W from global (k_prep).
// k_out: grid 2560, no LDS, bf16 W_out from global.
//
// ws layout (bytes):
//   [0,          +40M)  Q  bf16 [1024][640][32] (pre-scaled by SCALE*LOG2E)
//   [41943040,   +40M)  K  bf16 [1024][640][32]
//   [83886080,   +40M)  Vt bf16 [1024][32][640]
//   [125829120,  +40M)  O  bf16 [256][640][128] (head-major channels)
//   [167772160, +3.3M)  bias bf16 [4][160 jg][640 i][4]  (pre-x LOG2E)
//   [171048960, +96K)   W_qkv bf16 [384][128]
//   [171147264, +32K)   W_out bf16 [128][128]

typedef __attribute__((ext_vector_type(8)))  short short8;
typedef __attribute__((ext_vector_type(4)))  float f32x4;
typedef __attribute__((ext_vector_type(16))) float f32x16;

#define MFMA16(a, b, c) __builtin_amdgcn_mfma_f32_16x16x32_bf16((a), (b), (c), 0, 0, 0)
#define MFMA32(a, b, c) __builtin_amdgcn_mfma_f32_32x32x16_bf16((a), (b), (c), 0, 0, 0)

__device__ __forceinline__ unsigned short f2b(float f) {
  __hip_bfloat16 h = __float2bfloat16(f);
  return *reinterpret_cast<unsigned short*>(&h);
}
__device__ __forceinline__ float b2f(unsigned short s) {
  union { unsigned u; float f; } x; x.u = ((unsigned)s) << 16;
  return x.f;
}
__device__ __forceinline__ unsigned cvtpk(float lo, float hi) {
  unsigned r;
  asm("v_cvt_pk_bf16_f32 %0, %1, %2" : "=v"(r) : "v"(lo), "v"(hi));
  return r;
}
__device__ __forceinline__ void pl32swap(unsigned& a, unsigned& b) {
  asm("v_permlane32_swap_b32 %0, %1" : "+v"(a), "+v"(b));
}

constexpr float LOG2E_F = 1.4426950408889634f;
constexpr float QSCALE  = 0.17677669529663687f * 1.4426950408889634f;  // dh^-0.5 * log2(e)

// ---------------------------------------------------------------- weight cvt
__global__ __launch_bounds__(256) void k_prep(const float* __restrict__ wqkv,
                                              const float* __restrict__ wout,
                                              unsigned short* __restrict__ wq_bf,
                                              unsigned short* __restrict__ wo_bf) {
  int id = blockIdx.x * 256 + threadIdx.x;   // 65536 = 49152 + 16384
  if (id < 49152) wq_bf[id] = f2b(wqkv[id]);
  else            wo_bf[id - 49152] = f2b(wout[id - 49152]);
}

// ---------------------------------------------------------------- bias expand
// output: bt[h][jg][i][e] = LOG2E * table[idx[i][4jg+e]][h]; j>=625 -> -1e30,
// (j<625, i>=625) -> 0. Coalesced ushort4 writes; lane-consecutive i on read.
__global__ __launch_bounds__(256) void k_bias(const float* __restrict__ table,
                                              const int* __restrict__ idx,
                                              unsigned short* __restrict__ bt) {
  int id = blockIdx.x * 256 + threadIdx.x;   // 102400 over (jg, i)
  int jg = id / 640, i = id % 640;
  float v[4][4];                              // [e][h]
#pragma unroll
  for (int e = 0; e < 4; ++e) {
    int j = jg * 4 + e;
    if (j >= 625) {
#pragma unroll
      for (int h = 0; h < 4; ++h) v[e][h] = -1e30f;
    } else if (i >= 625) {
#pragma unroll
      for (int h = 0; h < 4; ++h) v[e][h] = 0.f;
    } else {
      const float* tr = table + idx[i * 625 + j] * 4;
#pragma unroll
      for (int h = 0; h < 4; ++h) v[e][h] = tr[h] * LOG2E_F;
    }
  }
#pragma unroll
  for (int h = 0; h < 4; ++h) {
    ushort4 p;
    p.x = f2b(v[0][h]); p.y = f2b(v[1][h]); p.z = f2b(v[2][h]); p.w = f2b(v[3][h]);
    *reinterpret_cast<ushort4*>(bt + (size_t)h * 409600 + (size_t)id * 4) = p;
  }
}

// ---------------------------------------------------------------- QKV proj
// one block per (batch, 64-row tile); x-tile staged f32 in LDS (coalesced);
// W bf16 read direct from global (L2-hot, shared by all blocks).
__global__ __launch_bounds__(256) void k_qkv(const float* __restrict__ x,
                                             const unsigned short* __restrict__ wbf,
                                             unsigned short* __restrict__ qws,
                                             unsigned short* __restrict__ kws,
                                             unsigned short* __restrict__ vtws) {
  __shared__ float Xf[128 * 65];             // 33.3 KB  [d][n] pad 65
  int blk = blockIdx.x;
  int b = blk / 10, tile = blk % 10;
  int t = threadIdx.x, w = t >> 6, lane = t & 63, r16 = lane & 15, g = lane >> 4;
  int n0 = tile * 64;
  const float* xb = x + (size_t)b * 80000;
  for (int it = 0; it < 32; ++it) {
    int idx = it * 256 + t;                  // 8192 = 128 d x 64 n
    int d = idx >> 6, nc = idx & 63;
    int n = n0 + nc;
    Xf[d * 65 + nc] = (n < 625) ? xb[d * 625 + n] : 0.f;
  }
  __syncthreads();
  int nr = n0 + w * 16;                      // wave's 16 rows
  short8 a[4];
#pragma unroll
  for (int kk = 0; kk < 4; ++kk) {
    short8 av;
#pragma unroll
    for (int jj = 0; jj < 8; ++jj)
      av[jj] = (short)f2b(Xf[(kk * 32 + g * 8 + jj) * 65 + w * 16 + r16]);
    a[kk] = av;
  }
  f32x4 acc[24];
#pragma unroll
  for (int nf = 0; nf < 24; ++nf) acc[nf] = (f32x4){0.f, 0.f, 0.f, 0.f};
#pragma unroll
  for (int kk = 0; kk < 4; ++kk) {
#pragma unroll
    for (int nf = 0; nf < 24; ++nf) {
      short8 bf = *reinterpret_cast<const short8*>(wbf + (nf * 16 + r16) * 128 + kk * 32 + g * 8);
      acc[nf] = MFMA16(a[kk], bf, acc[nf]);
    }
  }
#pragma unroll
  for (int nf = 0; nf < 24; ++nf) {
    int c0 = nf * 16;
    int sel = c0 >> 7, hh = (c0 & 127) >> 5, t0 = (c0 & 31);
    float mul = (sel == 0) ? QSCALE : 1.f;
    size_t base = (size_t)(b * 4 + hh);
    if (sel < 2) {
      unsigned short* dst = (sel ? kws : qws) + (base * 640 + nr + 4 * g) * 32 + t0 + r16;
#pragma unroll
      for (int rr = 0; rr < 4; ++rr) dst[rr * 32] = f2b(acc[nf][rr] * mul);
    } else {
      ushort4 pv;
      pv.x = f2b(acc[nf][0]); pv.y = f2b(acc[nf][1]);
      pv.z = f2b(acc[nf][2]); pv.w = f2b(acc[nf][3]);
      *reinterpret_cast<ushort4*>(vtws + (base * 32 + t0 + r16) * 640 + nr + 4 * g) = pv;
    }
  }
}

// ---------------------------------------------------------------- attention
// one block (512 thr, 8 waves) per (b,h); swapped 32x32 MFMA; P in registers.
__global__ __launch_bounds__(512) void k_attn(const unsigned short* __restrict__ qws,
                                              const unsigned short* __restrict__ kws,
                                              const unsigned short* __restrict__ vtws,
                                              const unsigned short* __restrict__ bt,
                                              unsigned short* __restrict__ ows) {
  __shared__ __align__(16) unsigned short Kl[640 * 40];   // 51.2 KB, pitch 80B
  __shared__ __align__(16) unsigned short Vl[32 * 648];   // 41.5 KB
  int bh = blockIdx.x, b = bh >> 2, h = bh & 3;
  int t = threadIdx.x, w = t >> 6, lane = t & 63;
  int i31 = lane & 31, hi = lane >> 5;
  const unsigned short* Kg = kws + (size_t)bh * 20480;
  const unsigned short* Vg = vtws + (size_t)bh * 20480;
  for (int it = 0; it < 5; ++it) {
    int idx = it * 512 + t;                  // 2560 8-elem blocks of K
    int row = idx >> 2, c8 = (idx & 3) * 8;
    *reinterpret_cast<short8*>(&Kl[row * 40 + c8]) =
        *reinterpret_cast<const short8*>(Kg + row * 32 + c8);
  }
  for (int it = 0; it < 5; ++it) {
    int idx = it * 512 + t;                  // 2560 8-elem blocks of V
    int d = idx / 80, nb = (idx % 80) * 8;
    *reinterpret_cast<short8*>(&Vl[d * 648 + nb]) =
        *reinterpret_cast<const short8*>(Vg + d * 640 + nb);
  }
  __syncthreads();
  const unsigned short* Qg = qws + (size_t)bh * 20480;
  const unsigned short* bth = bt + (size_t)h * 409600;
  short8 ones;
#pragma unroll
  for (int jj = 0; jj < 8; ++jj) ones[jj] = (short)0x3F80;  // bf16 1.0

  for (int ti = w; ti < 20; ti += 8) {       // wave's 32-row Q tiles
    int i = ti * 32 + i31;
    short8 qf0 = *reinterpret_cast<const short8*>(Qg + i * 32 + hi * 8);
    short8 qf1 = *reinterpret_cast<const short8*>(Qg + i * 32 + 16 + hi * 8);
    f32x16 oacc, sacc;
#pragma unroll
    for (int r = 0; r < 16; ++r) { oacc[r] = 0.f; sacc[r] = 0.f; }
    for (int c = 0; c < 5; ++c) {
      int j0 = c * 128;
      f32x16 s[4];
      // bias as C-operand: s[jt][4q+e] = bias^T[j0+32jt+8q+4hi+e][i]
#pragma unroll
      for (int jt = 0; jt < 4; ++jt) {
#pragma unroll
        for (int q = 0; q < 4; ++q) {
          int jg = (j0 >> 2) + jt * 8 + q * 2 + hi;
          ushort4 bv = *reinterpret_cast<const ushort4*>(bth + ((size_t)jg * 640 + i) * 4);
          s[jt][4 * q + 0] = b2f(bv.x);
          s[jt][4 * q + 1] = b2f(bv.y);
          s[jt][4 * q + 2] = b2f(bv.z);
          s[jt][4 * q + 3] = b2f(bv.w);
        }
      }
      // S^T = K Q^T + bias  (32x32 j-tiles, k = dh = 32 in two halves)
#pragma unroll
      for (int jt = 0; jt < 4; ++jt) {
        const unsigned short* kr = &Kl[(j0 + jt * 32 + i31) * 40 + hi * 8];
        short8 kf0 = *reinterpret_cast<const short8*>(kr);
        short8 kf1 = *reinterpret_cast<const short8*>(kr + 16);
        s[jt] = MFMA32(kf0, qf0, s[jt]);
        s[jt] = MFMA32(kf1, qf1, s[jt]);
      }
      // P = exp2(S') in place
#pragma unroll
      for (int jt = 0; jt < 4; ++jt)
#pragma unroll
        for (int r = 0; r < 16; ++r) s[jt][r] = __builtin_amdgcn_exp2f(s[jt][r]);
      // pack pairs: pk[jt][m][h2] = bf16x2 of P at j = 32jt + 8m + 4hi + 2h2 + {0,1}
      unsigned pk[4][4][2];
#pragma unroll
      for (int jt = 0; jt < 4; ++jt)
#pragma unroll
        for (int m = 0; m < 4; ++m) {
          pk[jt][m][0] = cvtpk(s[jt][4 * m + 0], s[jt][4 * m + 1]);
          pk[jt][m][1] = cvtpk(s[jt][4 * m + 2], s[jt][4 * m + 3]);
        }
      // PV + row-sum: 8 k-steps of 16
#pragma unroll
      for (int ks = 0; ks < 8; ++ks) {
        int jt = ks >> 1, mb = 2 * (ks & 1);
        unsigned a0 = pk[jt][mb][0],     a1 = pk[jt][mb][1];
        unsigned b0 = pk[jt][mb + 1][0], b1 = pk[jt][mb + 1][1];
        pl32swap(a0, b0);                    // (a0,b0) -> (w0, w2)
        pl32swap(a1, b1);                    // (a1,b1) -> (w1, w3)
        uint4 fr = make_uint4(a0, a1, b0, b1);
        short8 pfrag = *reinterpret_cast<short8*>(&fr);
        short8 vf = *reinterpret_cast<const short8*>(&Vl[i31 * 648 + j0 + ks * 16 + hi * 8]);
        oacc = MFMA32(vf, pfrag, oacc);      // O^T[d][i]
        sacc = MFMA32(ones, pfrag, sacc);    // every reg = row sum
      }
    }
    float rc = __builtin_amdgcn_rcpf(sacc[0]);
    size_t ob = ((size_t)b * 640 + i) * 128 + h * 32;
#pragma unroll
    for (int q = 0; q < 4; ++q)
#pragma unroll
      for (int h2 = 0; h2 < 2; ++h2) {
        unsigned pr = cvtpk(oacc[4 * q + 2 * h2] * rc, oacc[4 * q + 2 * h2 + 1] * rc);
        *reinterpret_cast<unsigned*>(ows + ob + q * 8 + hi * 4 + 2 * h2) = pr;
      }
  }
}

// ---------------------------------------------------------------- out proj
// one block per (batch, 64-row tile); W_out bf16 direct from global; no LDS.
__global__ __launch_bounds__(256) void k_out(const unsigned short* __restrict__ ows,
                                             const unsigned short* __restrict__ wbf,
                                             float* __restrict__ out) {
  int blk = blockIdx.x;
  int b = blk / 10, tile = blk % 10;
  int t = threadIdx.x, w = t >> 6, lane = t & 63, r16 = lane & 15, g = lane >> 4;
  const unsigned short* Ob = ows + (size_t)b * 640 * 128;
  float* outb = out + (size_t)b * 128 * 625;
  int n0 = tile * 64;
  f32x4 acc[2][4];
#pragma unroll
  for (int mi = 0; mi < 2; ++mi)
#pragma unroll
    for (int f = 0; f < 4; ++f) acc[mi][f] = (f32x4){0.f, 0.f, 0.f, 0.f};
#pragma unroll
  for (int kk = 0; kk < 4; ++kk) {
    short8 bfr[4];
#pragma unroll
    for (int f = 0; f < 4; ++f)
      bfr[f] = *reinterpret_cast<const short8*>(Ob + (n0 + f * 16 + r16) * 128 + kk * 32 + g * 8);
#pragma unroll
    for (int mi = 0; mi < 2; ++mi) {
      short8 afr = *reinterpret_cast<const short8*>(wbf + (w * 32 + mi * 16 + r16) * 128 + kk * 32 + g * 8);
#pragma unroll
      for (int f = 0; f < 4; ++f) acc[mi][f] = MFMA16(afr, bfr[f], acc[mi][f]);
    }
  }
#pragma unroll
  for (int mi = 0; mi < 2; ++mi)
#pragma unroll
    for (int f = 0; f < 4; ++f) {
      int n = n0 + f * 16 + r16;
      if (n < 625) {
        int dout = w * 32 + mi * 16 + 4 * g;
        outb[(dout + 0) * 625 + n] = acc[mi][f][0];
        outb[(dout + 1) * 625 + n] = acc[mi][f][1];
        outb[(dout + 2) * 625 + n] = acc[mi][f][2];
        outb[(dout + 3) * 625 + n] = acc[mi][f][3];
      }
    }
}

// ---------------------------------------------------------------- launch
extern "C" void kernel_launch(void* const* d_in, const int* in_sizes, int n_in,
                              void* d_out, int out_size, void* d_ws, size_t ws_size,
                              hipStream_t stream) {
  const float* x     = (const float*)d_in[0];
  const float* wqkv  = (const float*)d_in[1];
  const float* wout  = (const float*)d_in[2];
  const float* table = (const float*)d_in[3];
  const int*   idx   = (const int*)d_in[4];
  float* out = (float*)d_out;

  char* ws = (char*)d_ws;  // requires ~171.2 MB
  unsigned short* qws   = (unsigned short*)(ws);
  unsigned short* kws   = (unsigned short*)(ws + 41943040);
  unsigned short* vtws  = (unsigned short*)(ws + 83886080);
  unsigned short* ows   = (unsigned short*)(ws + 125829120);
  unsigned short* bt    = (unsigned short*)(ws + 167772160);
  unsigned short* wq_bf = (unsigned short*)(ws + 171048960);
  unsigned short* wo_bf = (unsigned short*)(ws + 171147264);

  k_prep<<<dim3(256), dim3(256), 0, stream>>>(wqkv, wout, wq_bf, wo_bf);
  k_bias<<<dim3(400), dim3(256), 0, stream>>>(table, idx, bt);
  k_qkv<<<dim3(2560), dim3(256), 0, stream>>>(x, wq_bf, qws, kws, vtws);
  k_attn<<<dim3(1024), dim3(512), 0, stream>>>(qws, kws, vtws, bt, ows);
  k_out<<<dim3(2560), dim3(256), 0, stream>>>(ows, wo_bf, out);
}

// Round 5
// 275.366 us; speedup vs baseline: 2.8386x; 1.3175x over previous
//
#include <hip/hip_runtime.h>
#include <hip/hip_bf16.h>

// Attention_44006234915573 — windowed attention, MI355X/gfx950
// B=256, D=128, HEADS=4, DH=32, N=625 (padded to 640).
//
// R5: k_qkv restructured — column-split waves, W prefetched into REGISTERS
// (24 frags/wave, disjoint, issued before the Xf stage so L2 latency hides
// under staging). LDS = Xf only (33KB -> 4 blocks/CU).
// k_attn (swapped 32x32 MFMA, in-register softmax) unchanged from R4.
//
// ws layout (bytes):
//   [0,          +40M)  Q  bf16 [1024][640][32] (pre-scaled by SCALE*LOG2E)
//   [41943040,   +40M)  K  bf16 [1024][640][32]
//   [83886080,   +40M)  Vt bf16 [1024][32][640]
//   [125829120,  +40M)  O  bf16 [256][640][128] (head-major channels)
//   [167772160, +3.3M)  bias bf16 [4][160 jg][640 i][4]  (pre-x LOG2E)
//   [171048960, +96K)   W_qkv bf16 [384][128]
//   [171147264, +32K)   W_out bf16 [128][128]

typedef __attribute__((ext_vector_type(8)))  short short8;
typedef __attribute__((ext_vector_type(4)))  float f32x4;
typedef __attribute__((ext_vector_type(16))) float f32x16;

#define MFMA16(a, b, c) __builtin_amdgcn_mfma_f32_16x16x32_bf16((a), (b), (c), 0, 0, 0)
#define MFMA32(a, b, c) __builtin_amdgcn_mfma_f32_32x32x16_bf16((a), (b), (c), 0, 0, 0)

__device__ __forceinline__ unsigned short f2b(float f) {
  __hip_bfloat16 h = __float2bfloat16(f);
  return *reinterpret_cast<unsigned short*>(&h);
}
__device__ __forceinline__ float b2f(unsigned short s) {
  union { unsigned u; float f; } x; x.u = ((unsigned)s) << 16;
  return x.f;
}
__device__ __forceinline__ unsigned cvtpk(float lo, float hi) {
  unsigned r;
  asm("v_cvt_pk_bf16_f32 %0, %1, %2" : "=v"(r) : "v"(lo), "v"(hi));
  return r;
}
__device__ __forceinline__ void pl32swap(unsigned& a, unsigned& b) {
  asm("v_permlane32_swap_b32 %0, %1" : "+v"(a), "+v"(b));
}

constexpr float LOG2E_F = 1.4426950408889634f;
constexpr float QSCALE  = 0.17677669529663687f * 1.4426950408889634f;  // dh^-0.5 * log2(e)

// ---------------------------------------------------------------- weight cvt
__global__ __launch_bounds__(256) void k_prep(const float* __restrict__ wqkv,
                                              const float* __restrict__ wout,
                                              unsigned short* __restrict__ wq_bf,
                                              unsigned short* __restrict__ wo_bf) {
  int id = blockIdx.x * 256 + threadIdx.x;   // 65536 = 49152 + 16384
  if (id < 49152) wq_bf[id] = f2b(wqkv[id]);
  else            wo_bf[id - 49152] = f2b(wout[id - 49152]);
}

// ---------------------------------------------------------------- bias expand
// output: bt[h][jg][i][e] = LOG2E * table[idx[i][4jg+e]][h]; j>=625 -> -1e30,
// (j<625, i>=625) -> 0. Coalesced ushort4 writes; lane-consecutive i on read.
__global__ __launch_bounds__(256) void k_bias(const float* __restrict__ table,
                                              const int* __restrict__ idx,
                                              unsigned short* __restrict__ bt) {
  int id = blockIdx.x * 256 + threadIdx.x;   // 102400 over (jg, i)
  int jg = id / 640, i = id % 640;
  float v[4][4];                              // [e][h]
#pragma unroll
  for (int e = 0; e < 4; ++e) {
    int j = jg * 4 + e;
    if (j >= 625) {
#pragma unroll
      for (int h = 0; h < 4; ++h) v[e][h] = -1e30f;
    } else if (i >= 625) {
#pragma unroll
      for (int h = 0; h < 4; ++h) v[e][h] = 0.f;
    } else {
      const float* tr = table + idx[i * 625 + j] * 4;
#pragma unroll
      for (int h = 0; h < 4; ++h) v[e][h] = tr[h] * LOG2E_F;
    }
  }
#pragma unroll
  for (int h = 0; h < 4; ++h) {
    ushort4 p;
    p.x = f2b(v[0][h]); p.y = f2b(v[1][h]); p.z = f2b(v[2][h]); p.w = f2b(v[3][h]);
    *reinterpret_cast<ushort4*>(bt + (size_t)h * 409600 + (size_t)id * 4) = p;
  }
}

// ---------------------------------------------------------------- QKV proj
// one block per (batch, 64-row tile); 4 waves, column-split: wave w owns
// nf = 6w..6w+5 and prefetches its 24 W fragments into registers BEFORE the
// x-stage (L2 latency hides under staging). Xf f32 in LDS for the transpose.
__global__ __launch_bounds__(256) void k_qkv(const float* __restrict__ x,
                                             const unsigned short* __restrict__ wbf,
                                             unsigned short* __restrict__ qws,
                                             unsigned short* __restrict__ kws,
                                             unsigned short* __restrict__ vtws) {
  __shared__ float Xf[128 * 65];             // 33.3 KB  [d][n] pad 65
  int blk = blockIdx.x;
  int b = blk / 10, tile = blk % 10;
  int t = threadIdx.x, w = t >> 6, lane = t & 63, r16 = lane & 15, g = lane >> 4;
  // prefetch this wave's W fragments (issued first; consumed after barrier)
  short8 wf[6][4];
#pragma unroll
  for (int f = 0; f < 6; ++f)
#pragma unroll
    for (int kk = 0; kk < 4; ++kk)
      wf[f][kk] = *reinterpret_cast<const short8*>(
          wbf + ((6 * w + f) * 16 + r16) * 128 + kk * 32 + g * 8);
  // stage x tile (coalesced 256B rows)
  int n0 = tile * 64;
  const float* xb = x + (size_t)b * 80000;
  for (int it = 0; it < 32; ++it) {
    int idx = it * 256 + t;                  // 8192 = 128 d x 64 n
    int d = idx >> 6, nc = idx & 63;
    int n = n0 + nc;
    Xf[d * 65 + nc] = (n < 625) ? xb[d * 625 + n] : 0.f;
  }
  __syncthreads();
  for (int rg = 0; rg < 4; ++rg) {           // 4 row-groups of 16
    int nr = n0 + rg * 16;
    short8 a[4];
#pragma unroll
    for (int kk = 0; kk < 4; ++kk) {
      short8 av;
#pragma unroll
      for (int jj = 0; jj < 8; ++jj)
        av[jj] = (short)f2b(Xf[(kk * 32 + g * 8 + jj) * 65 + rg * 16 + r16]);
      a[kk] = av;
    }
    f32x4 acc[6];
#pragma unroll
    for (int f = 0; f < 6; ++f) acc[f] = (f32x4){0.f, 0.f, 0.f, 0.f};
#pragma unroll
    for (int kk = 0; kk < 4; ++kk)
#pragma unroll
      for (int f = 0; f < 6; ++f)
        acc[f] = MFMA16(a[kk], wf[f][kk], acc[f]);
#pragma unroll
    for (int f = 0; f < 6; ++f) {
      int c0 = (6 * w + f) * 16;
      int sel = c0 >> 7, hh = (c0 & 127) >> 5, t0 = (c0 & 31);
      float mul = (sel == 0) ? QSCALE : 1.f;
      size_t base = (size_t)(b * 4 + hh);
      if (sel < 2) {
        unsigned short* dst = (sel ? kws : qws) + (base * 640 + nr + 4 * g) * 32 + t0 + r16;
#pragma unroll
        for (int rr = 0; rr < 4; ++rr) dst[rr * 32] = f2b(acc[f][rr] * mul);
      } else {
        ushort4 pv;
        pv.x = f2b(acc[f][0]); pv.y = f2b(acc[f][1]);
        pv.z = f2b(acc[f][2]); pv.w = f2b(acc[f][3]);
        *reinterpret_cast<ushort4*>(vtws + (base * 32 + t0 + r16) * 640 + nr + 4 * g) = pv;
      }
    }
  }
}

// ---------------------------------------------------------------- attention
// one block (512 thr, 8 waves) per (b,h); swapped 32x32 MFMA; P in registers.
__global__ __launch_bounds__(512) void k_attn(const unsigned short* __restrict__ qws,
                                              const unsigned short* __restrict__ kws,
                                              const unsigned short* __restrict__ vtws,
                                              const unsigned short* __restrict__ bt,
                                              unsigned short* __restrict__ ows) {
  __shared__ __align__(16) unsigned short Kl[640 * 40];   // 51.2 KB, pitch 80B
  __shared__ __align__(16) unsigned short Vl[32 * 648];   // 41.5 KB
  int bh = blockIdx.x, b = bh >> 2, h = bh & 3;
  int t = threadIdx.x, w = t >> 6, lane = t & 63;
  int i31 = lane & 31, hi = lane >> 5;
  const unsigned short* Kg = kws + (size_t)bh * 20480;
  const unsigned short* Vg = vtws + (size_t)bh * 20480;
  for (int it = 0; it < 5; ++it) {
    int idx = it * 512 + t;                  // 2560 8-elem blocks of K
    int row = idx >> 2, c8 = (idx & 3) * 8;
    *reinterpret_cast<short8*>(&Kl[row * 40 + c8]) =
        *reinterpret_cast<const short8*>(Kg + row * 32 + c8);
  }
  for (int it = 0; it < 5; ++it) {
    int idx = it * 512 + t;                  // 2560 8-elem blocks of V
    int d = idx / 80, nb = (idx % 80) * 8;
    *reinterpret_cast<short8*>(&Vl[d * 648 + nb]) =
        *reinterpret_cast<const short8*>(Vg + d * 640 + nb);
  }
  __syncthreads();
  const unsigned short* Qg = qws + (size_t)bh * 20480;
  const unsigned short* bth = bt + (size_t)h * 409600;
  short8 ones;
#pragma unroll
  for (int jj = 0; jj < 8; ++jj) ones[jj] = (short)0x3F80;  // bf16 1.0

  for (int ti = w; ti < 20; ti += 8) {       // wave's 32-row Q tiles
    int i = ti * 32 + i31;
    short8 qf0 = *reinterpret_cast<const short8*>(Qg + i * 32 + hi * 8);
    short8 qf1 = *reinterpret_cast<const short8*>(Qg + i * 32 + 16 + hi * 8);
    f32x16 oacc, sacc;
#pragma unroll
    for (int r = 0; r < 16; ++r) { oacc[r] = 0.f; sacc[r] = 0.f; }
    for (int c = 0; c < 5; ++c) {
      int j0 = c * 128;
      f32x16 s[4];
      // bias as C-operand: s[jt][4q+e] = bias^T[j0+32jt+8q+4hi+e][i]
#pragma unroll
      for (int jt = 0; jt < 4; ++jt) {
#pragma unroll
        for (int q = 0; q < 4; ++q) {
          int jg = (j0 >> 2) + jt * 8 + q * 2 + hi;
          ushort4 bv = *reinterpret_cast<const ushort4*>(bth + ((size_t)jg * 640 + i) * 4);
          s[jt][4 * q + 0] = b2f(bv.x);
          s[jt][4 * q + 1] = b2f(bv.y);
          s[jt][4 * q + 2] = b2f(bv.z);
          s[jt][4 * q + 3] = b2f(bv.w);
        }
      }
      // S^T = K Q^T + bias  (32x32 j-tiles, k = dh = 32 in two halves)
#pragma unroll
      for (int jt = 0; jt < 4; ++jt) {
        const unsigned short* kr = &Kl[(j0 + jt * 32 + i31) * 40 + hi * 8];
        short8 kf0 = *reinterpret_cast<const short8*>(kr);
        short8 kf1 = *reinterpret_cast<const short8*>(kr + 16);
        s[jt] = MFMA32(kf0, qf0, s[jt]);
        s[jt] = MFMA32(kf1, qf1, s[jt]);
      }
      // P = exp2(S') in place
#pragma unroll
      for (int jt = 0; jt < 4; ++jt)
#pragma unroll
        for (int r = 0; r < 16; ++r) s[jt][r] = __builtin_amdgcn_exp2f(s[jt][r]);
      // pack pairs: pk[jt][m][h2] = bf16x2 of P at j = 32jt + 8m + 4hi + 2h2 + {0,1}
      unsigned pk[4][4][2];
#pragma unroll
      for (int jt = 0; jt < 4; ++jt)
#pragma unroll
        for (int m = 0; m < 4; ++m) {
          pk[jt][m][0] = cvtpk(s[jt][4 * m + 0], s[jt][4 * m + 1]);
          pk[jt][m][1] = cvtpk(s[jt][4 * m + 2], s[jt][4 * m + 3]);
        }
      // PV + row-sum: 8 k-steps of 16
#pragma unroll
      for (int ks = 0; ks < 8; ++ks) {
        int jt = ks >> 1, mb = 2 * (ks & 1);
        unsigned a0 = pk[jt][mb][0],     a1 = pk[jt][mb][1];
        unsigned b0 = pk[jt][mb + 1][0], b1 = pk[jt][mb + 1][1];
        pl32swap(a0, b0);                    // (a0,b0) -> (w0, w2)
        pl32swap(a1, b1);                    // (a1,b1) -> (w1, w3)
        uint4 fr = make_uint4(a0, a1, b0, b1);
        short8 pfrag = *reinterpret_cast<short8*>(&fr);
        short8 vf = *reinterpret_cast<const short8*>(&Vl[i31 * 648 + j0 + ks * 16 + hi * 8]);
        oacc = MFMA32(vf, pfrag, oacc);      // O^T[d][i]
        sacc = MFMA32(ones, pfrag, sacc);    // every reg = row sum
      }
    }
    float rc = __builtin_amdgcn_rcpf(sacc[0]);
    size_t ob = ((size_t)b * 640 + i) * 128 + h * 32;
#pragma unroll
    for (int q = 0; q < 4; ++q)
#pragma unroll
      for (int h2 = 0; h2 < 2; ++h2) {
        unsigned pr = cvtpk(oacc[4 * q + 2 * h2] * rc, oacc[4 * q + 2 * h2 + 1] * rc);
        *reinterpret_cast<unsigned*>(ows + ob + q * 8 + hi * 4 + 2 * h2) = pr;
      }
  }
}

// ---------------------------------------------------------------- out proj
// one block per (batch, 64-row tile); W_out bf16 direct from global; no LDS.
__global__ __launch_bounds__(256) void k_out(const unsigned short* __restrict__ ows,
                                             const unsigned short* __restrict__ wbf,
                                             float* __restrict__ out) {
  int blk = blockIdx.x;
  int b = blk / 10, tile = blk % 10;
  int t = threadIdx.x, w = t >> 6, lane = t & 63, r16 = lane & 15, g = lane >> 4;
  const unsigned short* Ob = ows + (size_t)b * 640 * 128;
  float* outb = out + (size_t)b * 128 * 625;
  int n0 = tile * 64;
  f32x4 acc[2][4];
#pragma unroll
  for (int mi = 0; mi < 2; ++mi)
#pragma unroll
    for (int f = 0; f < 4; ++f) acc[mi][f] = (f32x4){0.f, 0.f, 0.f, 0.f};
#pragma unroll
  for (int kk = 0; kk < 4; ++kk) {
    short8 bfr[4];
#pragma unroll
    for (int f = 0; f < 4; ++f)
      bfr[f] = *reinterpret_cast<const short8*>(Ob + (n0 + f * 16 + r16) * 128 + kk * 32 + g * 8);
#pragma unroll
    for (int mi = 0; mi < 2; ++mi) {
      short8 afr = *reinterpret_cast<const short8*>(wbf + (w * 32 + mi * 16 + r16) * 128 + kk * 32 + g * 8);
#pragma unroll
      for (int f = 0; f < 4; ++f) acc[mi][f] = MFMA16(afr, bfr[f], acc[mi][f]);
    }
  }
#pragma unroll
  for (int mi = 0; mi < 2; ++mi)
#pragma unroll
    for (int f = 0; f < 4; ++f) {
      int n = n0 + f * 16 + r16;
      if (n < 625) {
        int dout = w * 32 + mi * 16 + 4 * g;
        outb[(dout + 0) * 625 + n] = acc[mi][f][0];
        outb[(dout + 1) * 625 + n] = acc[mi][f][1];
        outb[(dout + 2) * 625 + n] = acc[mi][f][2];
        outb[(dout + 3) * 625 + n] = acc[mi][f][3];
      }
    }
}

// ---------------------------------------------------------------- launch
extern "C" void kernel_launch(void* const* d_in, const int* in_sizes, int n_in,
                              void* d_out, int out_size, void* d_ws, size_t ws_size,
                              hipStream_t stream) {
  const float* x     = (const float*)d_in[0];
  const float* wqkv  = (const float*)d_in[1];
  const float* wout  = (const float*)d_in[2];
  const float* table = (const float*)d_in[3];
  const int*   idx   = (const int*)d_in[4];
  float* out = (float*)d_out;

  char* ws = (char*)d_ws;  // requires ~171.2 MB
  unsigned short* qws   = (unsigned short*)(ws);
  unsigned short* kws   = (unsigned short*)(ws + 41943040);
  unsigned short* vtws  = (unsigned short*)(ws + 83886080);
  unsigned short* ows   = (unsigned short*)(ws + 125829120);
  unsigned short* bt    = (unsigned short*)(ws + 167772160);
  unsigned short* wq_bf = (unsigned short*)(ws + 171048960);
  unsigned short* wo_bf = (unsigned short*)(ws + 171147264);

  k_prep<<<dim3(256), dim3(256), 0, stream>>>(wqkv, wout, wq_bf, wo_bf);
  k_bias<<<dim3(400), dim3(256), 0, stream>>>(table, idx, bt);
  k_qkv<<<dim3(2560), dim3(256), 0, stream>>>(x, wq_bf, qws, kws, vtws);
  k_attn<<<dim3(1024), dim3(512), 0, stream>>>(qws, kws, vtws, bt, ows);
  k_out<<<dim3(2560), dim3(256), 0, stream>>>(ows, wo_bf, out);
}